// Round 7
// baseline (180.396 us; speedup 1.0000x reference)
//
#include <hip/hip_runtime.h>
#include <math.h>

#define IMG 512
#define TW 64      // output tile width
#define TH 16      // output tile height
#define RAD 5
#define IH 26      // h-field rows = TH+10
#define HWP 68     // padded h-field row stride (16B-aligned rows)
#define NG (IH * (TW / 4))   // 26*16 = 416 horizontal tasks
#define MMB 1024   // minmax stage-1 blocks

struct W11 { float w[11]; };

__device__ __forceinline__ unsigned omap(float f) {
  unsigned b = __float_as_uint(f);
  return (b & 0x80000000u) ? ~b : (b | 0x80000000u);
}
__device__ __forceinline__ float ounmap(unsigned u) {
  return __uint_as_float((u & 0x80000000u) ? (u ^ 0x80000000u) : ~u);
}

// Stage 1: per-block partial min/max -> disjoint slots, no atomics.
__global__ __launch_bounds__(256) void minmax_part(const float4* __restrict__ img,
                                                   int n4, unsigned* __restrict__ part) {
  unsigned mx = 0u, mn = 0xFFFFFFFFu;
  int stride = gridDim.x * blockDim.x;
  for (int i = blockIdx.x * blockDim.x + threadIdx.x; i < n4; i += stride) {
    float4 v = img[i];
    unsigned a = omap(v.x), b = omap(v.y), c = omap(v.z), d = omap(v.w);
    mx = max(mx, max(max(a, b), max(c, d)));
    mn = min(mn, min(min(a, b), min(c, d)));
  }
  #pragma unroll
  for (int off = 32; off > 0; off >>= 1) {
    mx = max(mx, __shfl_down(mx, off));
    mn = min(mn, __shfl_down(mn, off));
  }
  __shared__ unsigned smx[4], smn[4];
  int lane = threadIdx.x & 63, wv = threadIdx.x >> 6;
  if (lane == 0) { smx[wv] = mx; smn[wv] = mn; }
  __syncthreads();
  if (threadIdx.x == 0) {
    mx = max(max(smx[0], smx[1]), max(smx[2], smx[3]));
    mn = min(min(smn[0], smn[1]), min(smn[2], smn[3]));
    part[2 * blockIdx.x]     = mx;
    part[2 * blockIdx.x + 1] = mn;
  }
}

// Stage 2: fold MMB partial pairs into ws[0]=max, ws[1]=min.
__global__ __launch_bounds__(256) void minmax_final(const unsigned* __restrict__ part,
                                                    unsigned* __restrict__ ws) {
  unsigned mx = 0u, mn = 0xFFFFFFFFu;
  for (int i = threadIdx.x; i < MMB; i += 256) {
    mx = max(mx, part[2 * i]);
    mn = min(mn, part[2 * i + 1]);
  }
  #pragma unroll
  for (int off = 32; off > 0; off >>= 1) {
    mx = max(mx, __shfl_down(mx, off));
    mn = min(mn, __shfl_down(mn, off));
  }
  __shared__ unsigned smx[4], smn[4];
  int lane = threadIdx.x & 63, wv = threadIdx.x >> 6;
  if (lane == 0) { smx[wv] = mx; smn[wv] = mn; }
  __syncthreads();
  if (threadIdx.x == 0) {
    ws[0] = max(max(smx[0], smx[1]), max(smx[2], smx[3]));
    ws[1] = min(min(smn[0], smn[1]), min(smn[2], smn[3]));
  }
}

// Fused SSIM. h-pass: direct global reads (L1 absorbs 4x overlap). LDS holds
// only the 5 h-fields. v-pass: 4 cols x 1 row per thread with ds_read_b128 —
// 3.44 LDS instr/output (was 30 scalar b32) so LDS and VALU can overlap
// instead of convoying. BS=256 + bounds(256,4): VGPR budget 128 for ILP.
__global__ __launch_bounds__(256, 4) void ssim_k(const float* __restrict__ img1,
                                                 const float* __restrict__ img2,
                                                 float* __restrict__ out,
                                                 const unsigned* __restrict__ ws,
                                                 W11 wv) {
  __shared__ float H[5][IH][HWP];   // h-conv of: x1, x2, x1^2, x2^2, x1*x2 (35.4KB)

  const int tid = threadIdx.x;
  const int bx = blockIdx.x, by = blockIdx.y, n = blockIdx.z;
  const float* p1 = img1 + (size_t)n * IMG * IMG;
  const float* p2 = img2 + (size_t)n * IMG * IMG;
  const int x0 = bx * TW - RAD;
  const int y0 = by * TH - RAD;

  const bool x_ok = (bx > 0) & (bx < IMG / TW - 1);
  const bool y_ok = (by > 0) & (by < IMG / TH - 1);

  // ---- C1/C2 scalar loads issued early; used after the barrier ----
  float L = ounmap(ws[0]) - ounmap(ws[1]);
  if (L == 0.f) L = 5.f;
  float C1 = 0.01f * L; C1 *= C1;
  float C2 = 0.03f * L; C2 *= C2;

  // ---- horizontal pass: 416 tasks of (1 row, 4 h-cols); 2 per thread ----
  #pragma unroll
  for (int it = 0; it < 2; ++it) {
    int g = tid + it * 256;
    if (g < NG) {
      int r = g >> 4;            // h-field row 0..25
      int xg = (g & 15) << 2;    // first of 4 h-field cols (0..60)
      int gy = y0 + r;

      float A20[20], B20[20];
      float* aa = &A20[3];       // aa[t] = input at global x = x0+xg+t
      float* bb = &B20[3];

      bool y_in = y_ok | ((gy >= 0) & (gy < IMG));
      if (!y_in) {
        #pragma unroll
        for (int t = 0; t < 14; ++t) { aa[t] = 0.f; bb[t] = 0.f; }
      } else if (x_ok) {
        // x0+xg-3 = bx*64 + xg - 8: multiple of 4 -> 16B-aligned float4 loads
        const float* r1 = p1 + gy * IMG + (x0 + xg - 3);
        const float* r2 = p2 + gy * IMG + (x0 + xg - 3);
        #pragma unroll
        for (int m = 0; m < 5; ++m) *(float4*)&A20[4 * m] = *(const float4*)(r1 + 4 * m);
        #pragma unroll
        for (int m = 0; m < 5; ++m) *(float4*)&B20[4 * m] = *(const float4*)(r2 + 4 * m);
      } else {
        const float* r1 = p1 + gy * IMG;
        const float* r2 = p2 + gy * IMG;
        #pragma unroll
        for (int t = 0; t < 14; ++t) {
          int x = x0 + xg + t;
          bool ok = (x >= 0) & (x < IMG);
          aa[t] = ok ? r1[x] : 0.f;
          bb[t] = ok ? r2[x] : 0.f;
        }
      }

      float a2[14], b2[14], ab[14];
      #pragma unroll
      for (int t = 0; t < 14; ++t) {
        a2[t] = aa[t] * aa[t]; b2[t] = bb[t] * bb[t]; ab[t] = aa[t] * bb[t];
      }

      float acc[5][4];
      #pragma unroll
      for (int f = 0; f < 5; ++f)
        #pragma unroll
        for (int j = 0; j < 4; ++j) acc[f][j] = 0.f;

      #pragma unroll
      for (int k = 0; k < 11; ++k) {
        float wk = wv.w[k];
        #pragma unroll
        for (int j = 0; j < 4; ++j) {
          acc[0][j] += wk * aa[j + k];
          acc[1][j] += wk * bb[j + k];
          acc[2][j] += wk * a2[j + k];
          acc[3][j] += wk * b2[j + k];
          acc[4][j] += wk * ab[j + k];
        }
      }
      #pragma unroll
      for (int f = 0; f < 5; ++f)
        *(float4*)&H[f][r][xg] = make_float4(acc[f][0], acc[f][1], acc[f][2], acc[f][3]);
    }
  }
  __syncthreads();   // the only barrier

  // ---- vertical pass: 256 threads = (4 consecutive cols, 1 row) each;
  // 55 ds_read_b128 per thread produce 4 outputs ----
  const int c4 = (tid & 15) << 2;   // col 0,4,...,60
  const int r  = tid >> 4;          // output row 0..15

  float4 acc[5];
  #pragma unroll
  for (int f = 0; f < 5; ++f) acc[f] = make_float4(0.f, 0.f, 0.f, 0.f);

  #pragma unroll
  for (int f = 0; f < 5; ++f) {
    #pragma unroll
    for (int k = 0; k < 11; ++k) {
      float wk = wv.w[k];
      float4 v = *(const float4*)&H[f][r + k][c4];
      acc[f].x += wk * v.x;
      acc[f].y += wk * v.y;
      acc[f].z += wk * v.z;
      acc[f].w += wk * v.w;
    }
  }

  const float* m1 = (const float*)&acc[0];
  const float* m2 = (const float*)&acc[1];
  const float* e11 = (const float*)&acc[2];
  const float* e22 = (const float*)&acc[3];
  const float* e12 = (const float*)&acc[4];

  float4 res;
  float* rp = (float*)&res;
  #pragma unroll
  for (int j = 0; j < 4; ++j) {
    float mu1 = m1[j], mu2 = m2[j];
    float mu1s = mu1 * mu1, mu2s = mu2 * mu2, mu12 = mu1 * mu2;
    float s1 = e11[j] - mu1s, s2 = e22[j] - mu2s, s12 = e12[j] - mu12;
    float num = (2.f * mu12 + C1) * (2.f * s12 + C2);
    float den = (mu1s + mu2s + C1) * (s1 + s2 + C2);
    rp[j] = num * __builtin_amdgcn_rcpf(den);   // |rel err| ~1e-7 << 1.7e-2 threshold
  }
  int gy = by * TH + r, gx = bx * TW + c4;
  *(float4*)&out[(size_t)n * IMG * IMG + (size_t)gy * IMG + gx] = res;
}

extern "C" void kernel_launch(void* const* d_in, const int* in_sizes, int n_in,
                              void* d_out, int out_size, void* d_ws, size_t ws_size,
                              hipStream_t stream) {
  const float* img1 = (const float*)d_in[0];
  const float* img2 = (const float*)d_in[1];
  float* out = (float*)d_out;
  unsigned* ws = (unsigned*)d_ws;          // [0..1]: final max/min; [16..]: partials
  unsigned* part = ws + 16;
  int n = in_sizes[0];             // 32*1*512*512
  int batch = n / (IMG * IMG);     // 32

  // Gaussian window, center at ws/2 = 5.5 (asymmetric!), normalized
  W11 wv;
  double g[11], s = 0.0;
  for (int i = 0; i < 11; ++i) { double d = i - 5.5; g[i] = exp(-(d * d) / 4.5); s += g[i]; }
  for (int i = 0; i < 11; ++i) wv.w[i] = (float)(g[i] / s);

  minmax_part<<<MMB, 256, 0, stream>>>((const float4*)img1, n / 4, part);
  minmax_final<<<1, 256, 0, stream>>>(part, ws);
  dim3 grid(IMG / TW, IMG / TH, batch);
  ssim_k<<<grid, 256, 0, stream>>>(img1, img2, out, ws, wv);
}